// Round 6
// baseline (832.002 us; speedup 1.0000x reference)
//
#include <hip/hip_runtime.h>
#include <hip/hip_bf16.h>
#include <math.h>

#define NN 50000
#define EE 640000
#define DD 128
#define NREL 8
#define NCLS 16
#define NBUCK (NREL * NN)              // 400000 buckets, key = rel*NN + dst
#define SCAN_NB ((NBUCK + 255) / 256)  // 1563

typedef __attribute__((ext_vector_type(8))) short short8;   // 8 bf16 = 4 VGPRs
typedef __attribute__((ext_vector_type(4))) float f32x4;    // MFMA acc

__device__ __forceinline__ float bf2f(ushort u) {
  return __uint_as_float(((unsigned)u) << 16);
}
__device__ __forceinline__ ushort f2b(float f) {  // RNE
  unsigned u = __float_as_uint(f);
  u += 0x7fff + ((u >> 16) & 1);
  return (ushort)(u >> 16);
}

// ---------- CSR build (key = rel*NN + dst; rel-major => per-(block,rel) edges contiguous) ----------

__global__ __launch_bounds__(256) void count_kernel(const int* __restrict__ ei,
                                                    const int* __restrict__ et,
                                                    int* __restrict__ cnt) {
  int t = blockIdx.x * 256 + threadIdx.x;
  if (t < EE) {
    int key = et[t] * NN + ei[EE + t];
    atomicAdd(&cnt[key], 1);
  }
}

__global__ __launch_bounds__(256) void scan1_kernel(const int* __restrict__ cnt,
                                                    int* __restrict__ off,
                                                    int* __restrict__ bsum) {
  __shared__ int s[256];
  const int tid = threadIdx.x;
  const int i = blockIdx.x * 256 + tid;
  int v = (i < NBUCK) ? cnt[i] : 0;
  s[tid] = v;
  __syncthreads();
#pragma unroll
  for (int o = 1; o < 256; o <<= 1) {
    int t2 = (tid >= o) ? s[tid - o] : 0;
    __syncthreads();
    s[tid] += t2;
    __syncthreads();
  }
  if (i < NBUCK) off[i] = s[tid] - v;
  if (tid == 255) bsum[blockIdx.x] = s[255];
}

__global__ __launch_bounds__(256) void scan2_kernel(const int* __restrict__ bsum,
                                                    int* __restrict__ bpre) {
  __shared__ int s[256];
  __shared__ int carry;
  const int tid = threadIdx.x;
  if (tid == 0) carry = 0;
  __syncthreads();
  const int chunks = (SCAN_NB + 255) / 256;
  for (int c = 0; c < chunks; c++) {
    int idx = c * 256 + tid;
    int v = (idx < SCAN_NB) ? bsum[idx] : 0;
    s[tid] = v;
    __syncthreads();
#pragma unroll
    for (int o = 1; o < 256; o <<= 1) {
      int t2 = (tid >= o) ? s[tid - o] : 0;
      __syncthreads();
      s[tid] += t2;
      __syncthreads();
    }
    if (idx < SCAN_NB) bpre[idx] = carry + s[tid] - v;
    __syncthreads();
    if (tid == 255) carry += s[255];
    __syncthreads();
  }
}

// also fills cursor (replaces d2d memcpy)
__global__ __launch_bounds__(256) void scan3_kernel(int* __restrict__ off,
                                                    const int* __restrict__ bpre,
                                                    int* __restrict__ cursor) {
  int i = blockIdx.x * 256 + threadIdx.x;
  if (i < NBUCK) {
    int o = off[i] + bpre[i >> 8];
    off[i] = o;
    cursor[i] = o;
  }
  if (i == 0) off[NBUCK] = EE;
}

// rec word0 = src | (dst&63)<<16 ; word1 = ew/cnt (final scale)
__global__ __launch_bounds__(256) void bucket_kernel(const int* __restrict__ ei,
                                                     const int* __restrict__ et,
                                                     const float* __restrict__ ew,
                                                     const int* __restrict__ cnt,
                                                     int* __restrict__ cursor,
                                                     uint2* __restrict__ rec) {
  int e = blockIdx.x * 256 + threadIdx.x;
  if (e >= EE) return;
  int dst = ei[EE + e];
  int key = et[e] * NN + dst;
  float scale = ew[e] / fmaxf((float)cnt[key], 1.0f);
  int pos = atomicAdd(&cursor[key], 1);
  rec[pos] = make_uint2((unsigned)ei[e] | ((unsigned)(dst & 63) << 16),
                        __float_as_uint(scale));
}

// ---------- pack x (bf16) + W1Tc + W2T, one kernel ----------
// W1Tc[n*1024 + r*128 + k] = bf16(W1[r][k][n]); W2T[j*128 + k] = bf16(W2[j>>4][k][j&15])
#define XQ (NN * DD / 4)  // 1,600,000 float4 units
__global__ __launch_bounds__(256) void pack_kernel(const float* __restrict__ x,
                                                   const float* __restrict__ W1,
                                                   const float* __restrict__ W2,
                                                   ushort* __restrict__ xb,
                                                   ushort* __restrict__ W1Tc,
                                                   ushort* __restrict__ W2T) {
  int t = blockIdx.x * 256 + threadIdx.x;
  if (t < XQ) {
    float4 v = *(const float4*)&x[(size_t)t * 4];
    *(ushort4*)&xb[(size_t)t * 4] = make_ushort4(f2b(v.x), f2b(v.y), f2b(v.z), f2b(v.w));
  } else if (t < XQ + NREL * DD * DD) {
    int t2 = t - XQ;
    int n = t2 >> 10, r = (t2 >> 7) & 7, k = t2 & 127;
    W1Tc[t2] = f2b(W1[r * 16384 + k * 128 + n]);
  } else if (t < XQ + NREL * DD * DD + DD * DD) {
    int t2 = t - XQ - NREL * DD * DD;
    int j = t2 >> 7, k = t2 & 127;
    W2T[t2] = f2b(W2[(j >> 4) * (DD * NCLS) + k * NCLS + (j & 15)]);
  }
}

// ---------- fused layer1+layer2 GEMM: H2 = bf16( relu(gather(x) @ W1) @ W2T ) ----------
// Block = 64 nodes. Per relation chunk: balanced edge-parallel gather with
// ds_add_f32 into fp32 LDS accumulator (no divergence), then MFMA w/ on-the-fly
// bf16 cvt. After 8 chunks: relu->bf16 in LDS, second MFMA vs W2T, store H2.
#define ASF_STRIDE 132                  // fp32, 528B row: 16B aligned, banks spread
__global__ __launch_bounds__(256) void fused1_kernel(const int* __restrict__ off,
                                                     const uint2* __restrict__ rec,
                                                     const ushort* __restrict__ xb,
                                                     const ushort* __restrict__ W1Tc,
                                                     const ushort* __restrict__ W2T,
                                                     ushort* __restrict__ H2) {
  __shared__ float AsF[64 * ASF_STRIDE];          // 33792 B, reused as ushort[64*136]
  __shared__ ushort Bs[128 * 136];                // 34816 B
  __shared__ uint2 ldsRec[256];                   // 2048 B
  ushort* AsU = (ushort*)AsF;

  const int tid = threadIdx.x;
  const int m0 = blockIdx.x * 64;
  const int mEnd = min(m0 + 64, NN);
  const int wave = tid >> 6, lane = tid & 63;
  const int lm = lane & 15, lkb = (lane >> 4) * 8;

  f32x4 acc[4][2];
#pragma unroll
  for (int m = 0; m < 4; m++)
#pragma unroll
    for (int j = 0; j < 2; j++) acc[m][j] = (f32x4){0.f, 0.f, 0.f, 0.f};

  for (int r = 0; r < NREL; r++) {
    __syncthreads();  // previous chunk's As/Bs reads complete
    // zero fp32 accumulator (each thread 32 floats)
#pragma unroll
    for (int i = 0; i < 8; i++) {
      int p = tid * 4 + i * 1024;     // covers 8192 of 8448; tail below
      AsF[p + 0] = 0.f; AsF[p + 1] = 0.f; AsF[p + 2] = 0.f; AsF[p + 3] = 0.f;
    }
    if (tid < 64) {                    // 8448 - 8192 = 256 remaining
      int p = 8192 + tid * 4;
      AsF[p + 0] = 0.f; AsF[p + 1] = 0.f; AsF[p + 2] = 0.f; AsF[p + 3] = 0.f;
    }
    // stage B chunk (W1Tc slice for relation r)
#pragma unroll
    for (int i = 0; i < 8; i++) {
      int seg = tid + i * 256;
      int row = seg >> 4, c8 = (seg & 15) * 8;
      *(uint4*)&Bs[row * 136 + c8] =
          *(const uint4*)&W1Tc[(size_t)row * 1024 + r * 128 + c8];
    }
    // balanced edge-parallel gather
    const int s0 = off[r * NN + m0];
    const int L = off[r * NN + mEnd] - s0;
    for (int base = 0; base < L; base += 256) {
      int n = min(256, L - base);
      __syncthreads();  // zeros/Bs visible; prior sub-chunk processing done
      if (tid < n) ldsRec[tid] = rec[s0 + base + tid];
      __syncthreads();
      for (int w = tid; w < n * 4; w += 256) {
        int e = w >> 2, cq = w & 3;
        uint2 q = ldsRec[e];
        int src = q.x & 0xffff;
        int dl = (q.x >> 16) & 63;
        float sc = __uint_as_float(q.y);
        const ushort* xr = &xb[(size_t)src * DD + cq * 32];
        float* dstp = &AsF[dl * ASF_STRIDE + cq * 32];
#pragma unroll
        for (int jj = 0; jj < 4; jj++) {
          uint4 h = *(const uint4*)&xr[jj * 8];
          atomicAdd(&dstp[jj * 8 + 0], sc * __uint_as_float(h.x << 16));
          atomicAdd(&dstp[jj * 8 + 1], sc * __uint_as_float(h.x & 0xffff0000u));
          atomicAdd(&dstp[jj * 8 + 2], sc * __uint_as_float(h.y << 16));
          atomicAdd(&dstp[jj * 8 + 3], sc * __uint_as_float(h.y & 0xffff0000u));
          atomicAdd(&dstp[jj * 8 + 4], sc * __uint_as_float(h.z << 16));
          atomicAdd(&dstp[jj * 8 + 5], sc * __uint_as_float(h.z & 0xffff0000u));
          atomicAdd(&dstp[jj * 8 + 6], sc * __uint_as_float(h.w << 16));
          atomicAdd(&dstp[jj * 8 + 7], sc * __uint_as_float(h.w & 0xffff0000u));
        }
      }
    }
    __syncthreads();  // gather done
    // MFMA on this chunk (A from fp32 LDS, cvt to bf16 per fragment)
#pragma unroll
    for (int k0 = 0; k0 < 128; k0 += 32) {
      short8 a[4];
#pragma unroll
      for (int m = 0; m < 4; m++) {
        const float* ap = &AsF[(m * 16 + lm) * ASF_STRIDE + k0 + lkb];
        float4 f0 = *(const float4*)ap;
        float4 f1 = *(const float4*)(ap + 4);
        short8 av;
        av[0] = (short)f2b(f0.x); av[1] = (short)f2b(f0.y);
        av[2] = (short)f2b(f0.z); av[3] = (short)f2b(f0.w);
        av[4] = (short)f2b(f1.x); av[5] = (short)f2b(f1.y);
        av[6] = (short)f2b(f1.z); av[7] = (short)f2b(f1.w);
        a[m] = av;
      }
#pragma unroll
      for (int j = 0; j < 2; j++) {
        short8 b = *(const short8*)&Bs[((wave * 2 + j) * 16 + lm) * 136 + k0 + lkb];
#pragma unroll
        for (int m = 0; m < 4; m++)
          acc[m][j] = __builtin_amdgcn_mfma_f32_16x16x32_bf16(a[m], b, acc[m][j], 0, 0, 0);
      }
    }
  }

  // ---- epilogue 1: relu -> bf16 A2 tile in LDS (AsU, stride 136) ----
  __syncthreads();
  const int rquad = (lane >> 4) * 4;
#pragma unroll
  for (int m = 0; m < 4; m++)
#pragma unroll
    for (int j = 0; j < 2; j++)
#pragma unroll
      for (int i = 0; i < 4; i++)
        AsU[(m * 16 + rquad + i) * 136 + wave * 32 + j * 16 + lm] =
            f2b(fmaxf(acc[m][j][i], 0.f));
  __syncthreads();

  // ---- layer-2 GEMM on the in-LDS A2 tile: stage W2T, MFMA, store H2 ----
#pragma unroll
  for (int i = 0; i < 8; i++) {
    int seg = tid + i * 256;
    int row = seg >> 4, c8 = (seg & 15) * 8;
    *(uint4*)&Bs[row * 136 + c8] = *(const uint4*)&W2T[(size_t)row * DD + c8];
  }
  __syncthreads();
  f32x4 acc2[4][2];
#pragma unroll
  for (int m = 0; m < 4; m++)
#pragma unroll
    for (int j = 0; j < 2; j++) acc2[m][j] = (f32x4){0.f, 0.f, 0.f, 0.f};
#pragma unroll
  for (int k0 = 0; k0 < 128; k0 += 32) {
    short8 a[4];
#pragma unroll
    for (int m = 0; m < 4; m++)
      a[m] = *(const short8*)&AsU[(m * 16 + lm) * 136 + k0 + lkb];
#pragma unroll
    for (int j = 0; j < 2; j++) {
      short8 b = *(const short8*)&Bs[((wave * 2 + j) * 16 + lm) * 136 + k0 + lkb];
#pragma unroll
      for (int m = 0; m < 4; m++)
        acc2[m][j] = __builtin_amdgcn_mfma_f32_16x16x32_bf16(a[m], b, acc2[m][j], 0, 0, 0);
    }
  }
  __syncthreads();
#pragma unroll
  for (int m = 0; m < 4; m++)
#pragma unroll
    for (int j = 0; j < 2; j++)
#pragma unroll
      for (int i = 0; i < 4; i++)
        AsU[(m * 16 + rquad + i) * 136 + wave * 32 + j * 16 + lm] = f2b(acc2[m][j][i]);
  __syncthreads();
#pragma unroll
  for (int i = 0; i < 4; i++) {
    int seg = tid + i * 256;
    int row = seg >> 4, c8 = (seg & 15) * 8;
    int gr = m0 + row;
    if (gr < NN) *(uint4*)&H2[(size_t)gr * DD + c8] = *(const uint4*)&AsU[row * 136 + c8];
  }
}

// ---------- gather2 + log_softmax: 64 nodes/block, flattened edge-parallel ----------
#define OA_STRIDE 17
__global__ __launch_bounds__(256) void gather2_kernel(const int* __restrict__ off,
                                                      const uint2* __restrict__ rec,
                                                      const ushort* __restrict__ H2,
                                                      float* __restrict__ out) {
  __shared__ float outAcc[64 * OA_STRIDE];  // 4352 B
  __shared__ uint2 ldsRec[256];
  const int tid = threadIdx.x;
  const int m0 = blockIdx.x * 64;
  const int mEnd = min(m0 + 64, NN);
  for (int i = tid; i < 64 * OA_STRIDE; i += 256) outAcc[i] = 0.f;

  for (int r = 0; r < NREL; r++) {
    const int s0 = off[r * NN + m0];
    const int L = off[r * NN + mEnd] - s0;
    for (int base = 0; base < L; base += 256) {
      int n = min(256, L - base);
      __syncthreads();
      if (tid < n) ldsRec[tid] = rec[s0 + base + tid];
      __syncthreads();
      if (tid < n) {
        uint2 q = ldsRec[tid];
        int src = q.x & 0xffff;
        int dl = (q.x >> 16) & 63;
        float sc = __uint_as_float(q.y);
        const ushort* hp = &H2[(size_t)src * DD + r * NCLS];
        uint4 h0 = *(const uint4*)hp;
        uint4 h1 = *(const uint4*)(hp + 8);
        float* op = &outAcc[dl * OA_STRIDE];
        atomicAdd(&op[0],  sc * __uint_as_float(h0.x << 16));
        atomicAdd(&op[1],  sc * __uint_as_float(h0.x & 0xffff0000u));
        atomicAdd(&op[2],  sc * __uint_as_float(h0.y << 16));
        atomicAdd(&op[3],  sc * __uint_as_float(h0.y & 0xffff0000u));
        atomicAdd(&op[4],  sc * __uint_as_float(h0.z << 16));
        atomicAdd(&op[5],  sc * __uint_as_float(h0.z & 0xffff0000u));
        atomicAdd(&op[6],  sc * __uint_as_float(h0.w << 16));
        atomicAdd(&op[7],  sc * __uint_as_float(h0.w & 0xffff0000u));
        atomicAdd(&op[8],  sc * __uint_as_float(h1.x << 16));
        atomicAdd(&op[9],  sc * __uint_as_float(h1.x & 0xffff0000u));
        atomicAdd(&op[10], sc * __uint_as_float(h1.y << 16));
        atomicAdd(&op[11], sc * __uint_as_float(h1.y & 0xffff0000u));
        atomicAdd(&op[12], sc * __uint_as_float(h1.z << 16));
        atomicAdd(&op[13], sc * __uint_as_float(h1.z & 0xffff0000u));
        atomicAdd(&op[14], sc * __uint_as_float(h1.w << 16));
        atomicAdd(&op[15], sc * __uint_as_float(h1.w & 0xffff0000u));
      }
    }
  }
  __syncthreads();

  // log_softmax: 16 lane-groups of 16; each group handles 4 nodes
  const int g = tid >> 4, c = tid & 15;
  for (int nloc = g; nloc < 64; nloc += 16) {
    int v = m0 + nloc;
    float val = outAcc[nloc * OA_STRIDE + c];
    float m = val;
#pragma unroll
    for (int mask = 8; mask >= 1; mask >>= 1) m = fmaxf(m, __shfl_xor(m, mask, 16));
    float ex = expf(val - m);
#pragma unroll
    for (int mask = 8; mask >= 1; mask >>= 1) ex += __shfl_xor(ex, mask, 16);
    if (v < NN) out[(size_t)v * NCLS + c] = val - m - logf(ex);
  }
}

extern "C" void kernel_launch(void* const* d_in, const int* in_sizes, int n_in,
                              void* d_out, int out_size, void* d_ws, size_t ws_size,
                              hipStream_t stream) {
  const float* x  = (const float*)d_in[0];
  const int*   ei = (const int*)d_in[1];
  const int*   et = (const int*)d_in[2];
  const float* ew = (const float*)d_in[3];
  const float* W1 = (const float*)d_in[4];
  const float* W2 = (const float*)d_in[5];
  float* out = (float*)d_out;
  float* ws = (float*)d_ws;

  // workspace layout (float-unit offsets; ~36 MB)
  int*    cnt    = (int*)ws;                   // 400000
  int*    off    = (int*)(ws + 400000);        // 400001
  int*    bsum   = (int*)(ws + 800004);        // 1563
  int*    bpre   = (int*)(ws + 801568);        // 1563
  int*    cursor = (int*)(ws + 803132);        // 400000
  uint2*  rec    = (uint2*)(ws + 1203132);     // 640000 uint2
  ushort* xb     = (ushort*)(ws + 2483132);    // NN*DD bf16
  ushort* W1Tc   = (ushort*)(ws + 5683132);    // 128*1024 bf16
  ushort* W2T    = (ushort*)(ws + 5748668);    // 128*128 bf16
  ushort* H2     = (ushort*)(ws + 5756860);    // NN*DD bf16

  hipMemsetAsync(cnt, 0, (size_t)NBUCK * sizeof(int), stream);

  count_kernel<<<(EE + 255) / 256, 256, 0, stream>>>(ei, et, cnt);
  scan1_kernel<<<SCAN_NB, 256, 0, stream>>>(cnt, off, bsum);
  scan2_kernel<<<1, 256, 0, stream>>>(bsum, bpre);
  scan3_kernel<<<SCAN_NB, 256, 0, stream>>>(off, bpre, cursor);
  bucket_kernel<<<(EE + 255) / 256, 256, 0, stream>>>(ei, et, ew, cnt, cursor, rec);

  const int packN = XQ + NREL * DD * DD + DD * DD;
  pack_kernel<<<(packN + 255) / 256, 256, 0, stream>>>(x, W1, W2, xb, W1Tc, W2T);

  fused1_kernel<<<(NN + 63) / 64, 256, 0, stream>>>(off, rec, xb, W1Tc, W2T, H2);
  gather2_kernel<<<(NN + 63) / 64, 256, 0, stream>>>(off, rec, H2, out);
}

// Round 7
// 551.082 us; speedup vs baseline: 1.5098x; 1.5098x over previous
//
#include <hip/hip_runtime.h>
#include <hip/hip_bf16.h>
#include <math.h>

#define NN 50000
#define EE 640000
#define DD 128
#define NREL 8
#define NCLS 16
#define NBUCK (NREL * NN)              // 400000 buckets, key = rel*NN + dst
#define SCAN_NB ((NBUCK + 255) / 256)  // 1563

typedef __attribute__((ext_vector_type(8))) short short8;   // 8 bf16 = 4 VGPRs
typedef __attribute__((ext_vector_type(4))) float f32x4;    // MFMA acc

__device__ __forceinline__ float bflo(unsigned u) { return __uint_as_float(u << 16); }
__device__ __forceinline__ float bfhi(unsigned u) { return __uint_as_float(u & 0xffff0000u); }
__device__ __forceinline__ float bf2f(ushort u) { return __uint_as_float(((unsigned)u) << 16); }
__device__ __forceinline__ ushort f2b(float f) {  // RNE
  unsigned u = __float_as_uint(f);
  u += 0x7fff + ((u >> 16) & 1);
  return (ushort)(u >> 16);
}

// ---------- CSR build (key = rel*NN + dst) ----------

__global__ __launch_bounds__(256) void count_kernel(const int* __restrict__ ei,
                                                    const int* __restrict__ et,
                                                    int* __restrict__ cnt) {
  int t = blockIdx.x * 256 + threadIdx.x;
  if (t < EE) {
    int key = et[t] * NN + ei[EE + t];
    atomicAdd(&cnt[key], 1);
  }
}

__global__ __launch_bounds__(256) void scan1_kernel(const int* __restrict__ cnt,
                                                    int* __restrict__ off,
                                                    int* __restrict__ bsum) {
  __shared__ int s[256];
  const int tid = threadIdx.x;
  const int i = blockIdx.x * 256 + tid;
  int v = (i < NBUCK) ? cnt[i] : 0;
  s[tid] = v;
  __syncthreads();
#pragma unroll
  for (int o = 1; o < 256; o <<= 1) {
    int t2 = (tid >= o) ? s[tid - o] : 0;
    __syncthreads();
    s[tid] += t2;
    __syncthreads();
  }
  if (i < NBUCK) off[i] = s[tid] - v;
  if (tid == 255) bsum[blockIdx.x] = s[255];
}

__global__ __launch_bounds__(256) void scan2_kernel(const int* __restrict__ bsum,
                                                    int* __restrict__ bpre) {
  __shared__ int s[256];
  __shared__ int carry;
  const int tid = threadIdx.x;
  if (tid == 0) carry = 0;
  __syncthreads();
  const int chunks = (SCAN_NB + 255) / 256;
  for (int c = 0; c < chunks; c++) {
    int idx = c * 256 + tid;
    int v = (idx < SCAN_NB) ? bsum[idx] : 0;
    s[tid] = v;
    __syncthreads();
#pragma unroll
    for (int o = 1; o < 256; o <<= 1) {
      int t2 = (tid >= o) ? s[tid - o] : 0;
      __syncthreads();
      s[tid] += t2;
      __syncthreads();
    }
    if (idx < SCAN_NB) bpre[idx] = carry + s[tid] - v;
    __syncthreads();
    if (tid == 255) carry += s[255];
    __syncthreads();
  }
}

__global__ __launch_bounds__(256) void scan3_kernel(int* __restrict__ off,
                                                    const int* __restrict__ bpre,
                                                    int* __restrict__ cursor) {
  int i = blockIdx.x * 256 + threadIdx.x;
  if (i < NBUCK) {
    int o = off[i] + bpre[i >> 8];
    off[i] = o;
    cursor[i] = o;
  }
  if (i == 0) off[NBUCK] = EE;
}

// rec = (src, raw edge weight); mean divisor = bucket length at use
__global__ __launch_bounds__(256) void bucket_kernel(const int* __restrict__ ei,
                                                     const int* __restrict__ et,
                                                     const float* __restrict__ ew,
                                                     int* __restrict__ cursor,
                                                     uint2* __restrict__ rec) {
  int e = blockIdx.x * 256 + threadIdx.x;
  if (e >= EE) return;
  int key = et[e] * NN + ei[EE + e];
  int pos = atomicAdd(&cursor[key], 1);
  rec[pos] = make_uint2((unsigned)ei[e], __float_as_uint(ew[e]));
}

// ---------- pack x (bf16) + W1Tc + W2T ----------
// W1Tc[n*1024 + r*128 + k] = bf16(W1[r][k][n]); W2T[j*128 + k] = bf16(W2[j>>4][k][j&15])
#define XQ (NN * DD / 4)
__global__ __launch_bounds__(256) void pack_kernel(const float* __restrict__ x,
                                                   const float* __restrict__ W1,
                                                   const float* __restrict__ W2,
                                                   ushort* __restrict__ xb,
                                                   ushort* __restrict__ W1Tc,
                                                   ushort* __restrict__ W2T) {
  int t = blockIdx.x * 256 + threadIdx.x;
  if (t < XQ) {
    float4 v = *(const float4*)&x[(size_t)t * 4];
    *(ushort4*)&xb[(size_t)t * 4] = make_ushort4(f2b(v.x), f2b(v.y), f2b(v.z), f2b(v.w));
  } else if (t < XQ + NREL * DD * DD) {
    int t2 = t - XQ;
    int n = t2 >> 10, r = (t2 >> 7) & 7, k = t2 & 127;
    W1Tc[t2] = f2b(W1[r * 16384 + k * 128 + n]);
  } else if (t < XQ + NREL * DD * DD + DD * DD) {
    int t2 = t - XQ - NREL * DD * DD;
    int j = t2 >> 7, k = t2 & 127;
    W2T[t2] = f2b(W2[(j >> 4) * (DD * NCLS) + k * NCLS + (j & 15)]);
  }
}

// ---------- fused layer1+layer2: H2 = bf16( relu(gather(x) @ W1cat) @ W2T ) ----------
// Block = 64 nodes, 4 waves. Per relation: wave-per-bucket gather (64 lanes span
// the 128-col row; 2 buckets walked concurrently for MLP; wave-uniform branches),
// then 16x16x32 bf16 MFMA. Layer-2 GEMM fused on the in-LDS tile.
__global__ __launch_bounds__(256) void fused1_kernel(const int* __restrict__ off,
                                                     const uint2* __restrict__ rec,
                                                     const ushort* __restrict__ xb,
                                                     const ushort* __restrict__ W1Tc,
                                                     const ushort* __restrict__ W2T,
                                                     ushort* __restrict__ H2) {
  __shared__ ushort AsU[64 * 136];     // 17408 B (gather tile / epilogue bounce)
  __shared__ ushort Bs[128 * 136];     // 34816 B
  uint* As32 = (uint*)AsU;             // row stride 68 uints

  const int tid = threadIdx.x;
  const int m0 = blockIdx.x * 64;
  const int wave = tid >> 6, lane = tid & 63;
  const int lm = lane & 15, lkb = (lane >> 4) * 8;

  f32x4 acc[4][2];
#pragma unroll
  for (int m = 0; m < 4; m++)
#pragma unroll
    for (int j = 0; j < 2; j++) acc[m][j] = (f32x4){0.f, 0.f, 0.f, 0.f};

  for (int r = 0; r < NREL; r++) {
    __syncthreads();  // previous chunk's As/Bs reads complete
    // stage W1Tc slice for relation r
#pragma unroll
    for (int i = 0; i < 8; i++) {
      int seg = tid + i * 256;
      int row = seg >> 4, c8 = (seg & 15) * 8;
      *(uint4*)&Bs[row * 136 + c8] =
          *(const uint4*)&W1Tc[(size_t)row * 1024 + r * 128 + c8];
    }
    // wave-per-bucket gather: wave handles nodes wave*16..+15, two at a time
#pragma unroll 1
    for (int p = 0; p < 8; p++) {
      int n0 = wave * 16 + p, n1 = n0 + 8;
      int v0 = m0 + n0, v1 = m0 + n1;
      int s0 = 0, l0 = 0, s1 = 0, l1 = 0;
      float inv0 = 0.f, inv1 = 0.f;
      if (v0 < NN) {
        int b = r * NN + v0;
        s0 = off[b]; l0 = off[b + 1] - s0;
        inv0 = 1.0f / fmaxf((float)l0, 1.0f);
      }
      if (v1 < NN) {
        int b = r * NN + v1;
        s1 = off[b]; l1 = off[b + 1] - s1;
        inv1 = 1.0f / fmaxf((float)l1, 1.0f);
      }
      float a00 = 0.f, a01 = 0.f, a10 = 0.f, a11 = 0.f;
      int mx = max(l0, l1);
      for (int j = 0; j < mx; j++) {       // wave-uniform trip count & branches
        if (j < l0) {
          uint2 q = rec[s0 + j];
          float sc = __uint_as_float(q.y) * inv0;
          unsigned u = *(const unsigned*)&xb[(size_t)q.x * DD + lane * 2];
          a00 = fmaf(sc, bflo(u), a00);
          a01 = fmaf(sc, bfhi(u), a01);
        }
        if (j < l1) {
          uint2 q = rec[s1 + j];
          float sc = __uint_as_float(q.y) * inv1;
          unsigned u = *(const unsigned*)&xb[(size_t)q.x * DD + lane * 2];
          a10 = fmaf(sc, bflo(u), a10);
          a11 = fmaf(sc, bfhi(u), a11);
        }
      }
      As32[n0 * 68 + lane] = (unsigned)f2b(a00) | ((unsigned)f2b(a01) << 16);
      As32[n1 * 68 + lane] = (unsigned)f2b(a10) | ((unsigned)f2b(a11) << 16);
    }
    __syncthreads();
    // MFMA on this chunk
#pragma unroll
    for (int k0 = 0; k0 < 128; k0 += 32) {
      short8 a[4];
#pragma unroll
      for (int m = 0; m < 4; m++)
        a[m] = *(const short8*)&AsU[(m * 16 + lm) * 136 + k0 + lkb];
#pragma unroll
      for (int j = 0; j < 2; j++) {
        short8 b = *(const short8*)&Bs[((wave * 2 + j) * 16 + lm) * 136 + k0 + lkb];
#pragma unroll
        for (int m = 0; m < 4; m++)
          acc[m][j] = __builtin_amdgcn_mfma_f32_16x16x32_bf16(a[m], b, acc[m][j], 0, 0, 0);
      }
    }
  }

  // ---- epilogue 1: relu -> bf16 A2 tile in LDS ----
  __syncthreads();
  const int rquad = (lane >> 4) * 4;
#pragma unroll
  for (int m = 0; m < 4; m++)
#pragma unroll
    for (int j = 0; j < 2; j++)
#pragma unroll
      for (int i = 0; i < 4; i++)
        AsU[(m * 16 + rquad + i) * 136 + wave * 32 + j * 16 + lm] =
            f2b(fmaxf(acc[m][j][i], 0.f));
  __syncthreads();

  // ---- layer-2 GEMM on the in-LDS A2 tile ----
#pragma unroll
  for (int i = 0; i < 8; i++) {
    int seg = tid + i * 256;
    int row = seg >> 4, c8 = (seg & 15) * 8;
    *(uint4*)&Bs[row * 136 + c8] = *(const uint4*)&W2T[(size_t)row * DD + c8];
  }
  __syncthreads();
  f32x4 acc2[4][2];
#pragma unroll
  for (int m = 0; m < 4; m++)
#pragma unroll
    for (int j = 0; j < 2; j++) acc2[m][j] = (f32x4){0.f, 0.f, 0.f, 0.f};
#pragma unroll
  for (int k0 = 0; k0 < 128; k0 += 32) {
    short8 a[4];
#pragma unroll
    for (int m = 0; m < 4; m++)
      a[m] = *(const short8*)&AsU[(m * 16 + lm) * 136 + k0 + lkb];
#pragma unroll
    for (int j = 0; j < 2; j++) {
      short8 b = *(const short8*)&Bs[((wave * 2 + j) * 16 + lm) * 136 + k0 + lkb];
#pragma unroll
      for (int m = 0; m < 4; m++)
        acc2[m][j] = __builtin_amdgcn_mfma_f32_16x16x32_bf16(a[m], b, acc2[m][j], 0, 0, 0);
    }
  }
  __syncthreads();
#pragma unroll
  for (int m = 0; m < 4; m++)
#pragma unroll
    for (int j = 0; j < 2; j++)
#pragma unroll
      for (int i = 0; i < 4; i++)
        AsU[(m * 16 + rquad + i) * 136 + wave * 32 + j * 16 + lm] = f2b(acc2[m][j][i]);
  __syncthreads();
#pragma unroll
  for (int i = 0; i < 4; i++) {
    int seg = tid + i * 256;
    int row = seg >> 4, c8 = (seg & 15) * 8;
    int gr = m0 + row;
    if (gr < NN) *(uint4*)&H2[(size_t)gr * DD + c8] = *(const uint4*)&AsU[row * 136 + c8];
  }
}

// ---------- gather2 + log_softmax ----------
// Block = 4 waves = 8 nodes. Wave: 2 nodes, 8 rels; lane = (edge-slot e4 = lane>>4,
// col c = lane&15); 4 edges in flight; shfl_xor reduces slots; fused log-softmax.
__global__ __launch_bounds__(256) void gather2_kernel(const int* __restrict__ off,
                                                      const uint2* __restrict__ rec,
                                                      const ushort* __restrict__ H2,
                                                      float* __restrict__ out) {
  const int tid = threadIdx.x;
  const int wave = tid >> 6, lane = tid & 63;
  const int e4 = lane >> 4, c = lane & 15;
  const int v0 = blockIdx.x * 8 + wave * 2;
  const int v1 = v0 + 1;
  float acc0 = 0.f, acc1 = 0.f;

  for (int r = 0; r < NREL; r++) {
    int s0 = 0, l0 = 0, s1 = 0, l1 = 0;
    float inv0 = 0.f, inv1 = 0.f;
    if (v0 < NN) {
      int b = r * NN + v0;
      s0 = off[b]; l0 = off[b + 1] - s0;
      inv0 = 1.0f / fmaxf((float)l0, 1.0f);
    }
    if (v1 < NN) {
      int b = r * NN + v1;
      s1 = off[b]; l1 = off[b + 1] - s1;
      inv1 = 1.0f / fmaxf((float)l1, 1.0f);
    }
    int mx = max(l0, l1);
    for (int base = 0; base < mx; base += 4) {   // wave-uniform
      int i0 = base + e4, i1 = base + e4;
      if (i0 < l0) {
        uint2 q = rec[s0 + i0];
        acc0 = fmaf(__uint_as_float(q.y) * inv0,
                    bf2f(H2[(size_t)q.x * DD + r * NCLS + c]), acc0);
      }
      if (i1 < l1) {
        uint2 q = rec[s1 + i1];
        acc1 = fmaf(__uint_as_float(q.y) * inv1,
                    bf2f(H2[(size_t)q.x * DD + r * NCLS + c]), acc1);
      }
    }
  }
  // reduce across the 4 edge-slots
  acc0 += __shfl_xor(acc0, 16);
  acc0 += __shfl_xor(acc0, 32);
  acc1 += __shfl_xor(acc1, 16);
  acc1 += __shfl_xor(acc1, 32);

  float val = (e4 == 0) ? acc0 : acc1;  // group 0 -> v0, group 1 -> v1
  float m = val;
#pragma unroll
  for (int mask = 8; mask >= 1; mask >>= 1) m = fmaxf(m, __shfl_xor(m, mask, 16));
  float ex = expf(val - m);
#pragma unroll
  for (int mask = 8; mask >= 1; mask >>= 1) ex += __shfl_xor(ex, mask, 16);
  int vv = (e4 == 0) ? v0 : v1;
  if (lane < 32 && vv < NN) out[(size_t)vv * NCLS + c] = val - m - logf(ex);
}

extern "C" void kernel_launch(void* const* d_in, const int* in_sizes, int n_in,
                              void* d_out, int out_size, void* d_ws, size_t ws_size,
                              hipStream_t stream) {
  const float* x  = (const float*)d_in[0];
  const int*   ei = (const int*)d_in[1];
  const int*   et = (const int*)d_in[2];
  const float* ew = (const float*)d_in[3];
  const float* W1 = (const float*)d_in[4];
  const float* W2 = (const float*)d_in[5];
  float* out = (float*)d_out;
  float* ws = (float*)d_ws;

  // workspace layout (float-unit offsets; ~36 MB)
  int*    cnt    = (int*)ws;                   // 400000
  int*    off    = (int*)(ws + 400000);        // 400001
  int*    bsum   = (int*)(ws + 800004);        // 1563
  int*    bpre   = (int*)(ws + 801568);        // 1563
  int*    cursor = (int*)(ws + 803132);        // 400000
  uint2*  rec    = (uint2*)(ws + 1203132);     // 640000 uint2
  ushort* xb     = (ushort*)(ws + 2483132);    // NN*DD bf16
  ushort* W1Tc   = (ushort*)(ws + 5683132);    // 128*1024 bf16
  ushort* W2T    = (ushort*)(ws + 5748668);    // 128*128 bf16
  ushort* H2     = (ushort*)(ws + 5756860);    // NN*DD bf16

  hipMemsetAsync(cnt, 0, (size_t)NBUCK * sizeof(int), stream);

  count_kernel<<<(EE + 255) / 256, 256, 0, stream>>>(ei, et, cnt);
  scan1_kernel<<<SCAN_NB, 256, 0, stream>>>(cnt, off, bsum);
  scan2_kernel<<<1, 256, 0, stream>>>(bsum, bpre);
  scan3_kernel<<<SCAN_NB, 256, 0, stream>>>(off, bpre, cursor);
  bucket_kernel<<<(EE + 255) / 256, 256, 0, stream>>>(ei, et, ew, cursor, rec);

  const int packN = XQ + NREL * DD * DD + DD * DD;
  pack_kernel<<<(packN + 255) / 256, 256, 0, stream>>>(x, W1, W2, xb, W1Tc, W2T);

  fused1_kernel<<<(NN + 63) / 64, 256, 0, stream>>>(off, rec, xb, W1Tc, W2T, H2);
  gather2_kernel<<<(NN + 7) / 8, 256, 0, stream>>>(off, rec, H2, out);
}